// Round 1
// baseline (302.243 us; speedup 1.0000x reference)
//
#include <hip/hip_runtime.h>
#include <math.h>

#define BB 4
#define CC 256
#define LL 4096
#define DD 32   // q/k channels

typedef __attribute__((ext_vector_type(8))) short short8;  // 8 bf16 (4 VGPRs)
typedef __attribute__((ext_vector_type(4))) float f32x4;

__device__ inline unsigned short f2bf(float f) {
  union { float f; unsigned u; } v; v.f = f;
  unsigned r = v.u + 0x7fffu + ((v.u >> 16) & 1u);  // round-to-nearest-even
  return (unsigned short)(r >> 16);
}

// ---------------- kernel 1: QKV pointwise projection ----------------
// grid: BB * (LL/64) * 8  (b, 64-wide i-tile, 40-row o-split), 256 thr
// o in [0,32)->q, [32,64)->k, [64,320)->v rows 0..255
__global__ __launch_bounds__(256) void qkv_kernel(
    const float* __restrict__ x,
    const float* __restrict__ Wq, const float* __restrict__ bq,
    const float* __restrict__ Wk, const float* __restrict__ bk,
    const float* __restrict__ Wv, const float* __restrict__ bv,
    unsigned short* __restrict__ qT, unsigned short* __restrict__ kT,
    unsigned short* __restrict__ vv)
{
  __shared__ float ws[40 * 256];   // 40 KB W tile
  const int t   = threadIdx.x;
  const int blk = blockIdx.x;
  const int it  = blk & 63;
  const int os  = (blk >> 6) & 7;
  const int b   = blk >> 9;
  const int i0  = it * 64;
  const int og0 = os * 40;

  // stage 40 W rows into LDS (coalesced 1KB rows)
  for (int r = 0; r < 40; ++r) {
    int o = og0 + r;
    const float* src = (o < 32) ? (Wq + o * CC)
                     : (o < 64) ? (Wk + (o - 32) * CC)
                                : (Wv + (o - 64) * CC);
    ws[r * 256 + t] = src[t];
  }
  __syncthreads();

  const int i = t & 63;    // column within i-tile (whole wave shares g)
  const int g = t >> 6;    // 0..3 -> 10 outputs each
  float acc[10];
  #pragma unroll
  for (int u = 0; u < 10; ++u) {
    int o = og0 + g * 10 + u;
    acc[u] = (o < 32) ? bq[o] : (o < 64) ? bk[o - 32] : bv[o - 64];
  }
  const float* xcol = x + ((size_t)b * CC) * LL + i0 + i;
  for (int c = 0; c < 256; c += 4) {
    float x0 = xcol[(size_t)(c + 0) * LL];   // 256B coalesced per wave, L1-shared across waves
    float x1 = xcol[(size_t)(c + 1) * LL];
    float x2 = xcol[(size_t)(c + 2) * LL];
    float x3 = xcol[(size_t)(c + 3) * LL];
    #pragma unroll
    for (int u = 0; u < 10; ++u) {
      const f32x4 w4 = *(const f32x4*)&ws[(g * 10 + u) * 256 + c];  // wave-uniform -> LDS broadcast
      acc[u] += w4.x * x0 + w4.y * x1 + w4.z * x2 + w4.w * x3;
    }
  }
  #pragma unroll
  for (int u = 0; u < 10; ++u) {
    int o = og0 + g * 10 + u;
    unsigned short bf = f2bf(acc[u]);
    if (o < 32)       qT[((size_t)b * LL + i0 + i) * DD + o] = bf;           // qT[b][i][c8]
    else if (o < 64)  kT[((size_t)b * LL + i0 + i) * DD + (o - 32)] = bf;    // kT[b][j][c8]
    else              vv[((size_t)b * CC + (o - 64)) * LL + i0 + i] = bf;    // v[b][c][j]
  }
}

// ---------------- kernel 2: flash attention + residual epilogue ----------------
// grid: BB * (LL/64) blocks (one 64-query tile each), 256 thr = 4 waves.
// wave w: owns S rows 16w..16w+15 (queries) and O rows 64w..64w+63 (channels).
__global__ __launch_bounds__(256) void attn_kernel(
    const unsigned short* __restrict__ qT, const unsigned short* __restrict__ kT,
    const unsigned short* __restrict__ vv, const float* __restrict__ x,
    const float* __restrict__ gamma_p, float* __restrict__ out)
{
  // stride 72 bf16 (144 B): quarter-wave b128 reads land 2-way on banks (free)
  __shared__ __align__(16) unsigned short P_lds[64][72];
  __shared__ float alpha_lds[64];
  __shared__ float l_lds[64];

  const int t    = threadIdx.x;
  const int w    = t >> 6;
  const int lane = t & 63;
  const int q4   = lane >> 4;   // k-chunk selector in A/B frags
  const int cl   = lane & 15;   // m (A) / n (B) / col (C)
  const int blk  = blockIdx.x;
  const int it   = blk & 63;
  const int b    = blk >> 6;
  const int i0   = it * 64;

  // Q A-frag: A[m=cl][k=q4*8+tt] = q[c][i0+16w+cl]; contiguous 16B from qT
  short8 qa = *(const short8*)(qT + ((size_t)b * LL + i0 + 16 * w + cl) * DD + q4 * 8);

  f32x4 O[4][4];
  const f32x4 zero = {0.f, 0.f, 0.f, 0.f};
  #pragma unroll
  for (int mt = 0; mt < 4; ++mt)
    #pragma unroll
    for (int nt = 0; nt < 4; ++nt) O[mt][nt] = zero;

  float m_r[4] = {-INFINITY, -INFINITY, -INFINITY, -INFINITY};
  float l_r[4] = {0.f, 0.f, 0.f, 0.f};

  for (int jt = 0; jt < LL / 64; ++jt) {
    const int j0 = jt * 64;

    // prefetch V A-frags early (used after softmax -> long latency hidden)
    short8 va[4][2];
    #pragma unroll
    for (int mt = 0; mt < 4; ++mt)
      #pragma unroll
      for (int kk = 0; kk < 2; ++kk)
        va[mt][kk] = *(const short8*)(vv + ((size_t)b * CC + 64 * w + 16 * mt + cl) * LL
                                      + j0 + kk * 32 + q4 * 8);

    // S = Q^T K : one K=32 MFMA per 16x16 j-tile
    f32x4 s[4];
    #pragma unroll
    for (int nt = 0; nt < 4; ++nt) {
      short8 kb = *(const short8*)(kT + ((size_t)b * LL + j0 + 16 * nt + cl) * DD + q4 * 8);
      s[nt] = __builtin_amdgcn_mfma_f32_16x16x32_bf16(qa, kb, zero, 0, 0, 0);
    }

    // online softmax; row = 4*q4 + r, cols spread over the 16-lane group
    float al[4];
    #pragma unroll
    for (int r = 0; r < 4; ++r) {
      float m0 = fmaxf(fmaxf(s[0][r], s[1][r]), fmaxf(s[2][r], s[3][r]));
      m0 = fmaxf(m0, __shfl_xor(m0, 1, 16));
      m0 = fmaxf(m0, __shfl_xor(m0, 2, 16));
      m0 = fmaxf(m0, __shfl_xor(m0, 4, 16));
      m0 = fmaxf(m0, __shfl_xor(m0, 8, 16));
      float mn = fmaxf(m_r[r], m0);
      al[r] = __expf(m_r[r] - mn);   // first iter: exp(-inf)=0
      m_r[r] = mn;
      float acc = 0.f;
      #pragma unroll
      for (int nt = 0; nt < 4; ++nt) {
        float p = __expf(s[nt][r] - mn);
        s[nt][r] = p;
        acc += p;
      }
      acc += __shfl_xor(acc, 1, 16);
      acc += __shfl_xor(acc, 2, 16);
      acc += __shfl_xor(acc, 4, 16);
      acc += __shfl_xor(acc, 8, 16);
      l_r[r] = l_r[r] * al[r] + acc;
    }
    if (cl == 0) {
      #pragma unroll
      for (int r = 0; r < 4; ++r) alpha_lds[16 * w + 4 * q4 + r] = al[r];
    }
    #pragma unroll
    for (int nt = 0; nt < 4; ++nt)
      #pragma unroll
      for (int r = 0; r < 4; ++r)
        P_lds[16 * w + 4 * q4 + r][16 * nt + cl] = f2bf(s[nt][r]);

    __syncthreads();

    // rescale O columns (queries) by alpha
    float acol[4];
    #pragma unroll
    for (int nt = 0; nt < 4; ++nt) acol[nt] = alpha_lds[16 * nt + cl];  // same-addr broadcast
    #pragma unroll
    for (int mt = 0; mt < 4; ++mt)
      #pragma unroll
      for (int nt = 0; nt < 4; ++nt)
        #pragma unroll
        for (int r = 0; r < 4; ++r) O[mt][nt][r] *= acol[nt];

    // P as B-operand: B[k=j][n=i] = P[i][j] ; 16B ds_read_b128 per frag
    short8 pb[4][2];
    #pragma unroll
    for (int nt = 0; nt < 4; ++nt)
      #pragma unroll
      for (int kk = 0; kk < 2; ++kk)
        pb[nt][kk] = *(const short8*)&P_lds[16 * nt + cl][kk * 32 + q4 * 8];

    // O += V * P^T  (M=c, N=i, K=j ; Tj=64 -> 2 K-steps)
    #pragma unroll
    for (int mt = 0; mt < 4; ++mt)
      #pragma unroll
      for (int kk = 0; kk < 2; ++kk)
        #pragma unroll
        for (int nt = 0; nt < 4; ++nt)
          O[mt][nt] = __builtin_amdgcn_mfma_f32_16x16x32_bf16(va[mt][kk], pb[nt][kk],
                                                              O[mt][nt], 0, 0, 0);

    __syncthreads();   // protect P_lds/alpha before next tile overwrites
  }

  // epilogue: out = gamma * O/l + x
  if (cl == 0) {
    #pragma unroll
    for (int r = 0; r < 4; ++r) l_lds[16 * w + 4 * q4 + r] = l_r[r];
  }
  __syncthreads();
  float inv_l[4];
  #pragma unroll
  for (int nt = 0; nt < 4; ++nt) inv_l[nt] = 1.0f / l_lds[16 * nt + cl];
  const float gam = gamma_p[0];
  #pragma unroll
  for (int mt = 0; mt < 4; ++mt) {
    const int c = 64 * w + 16 * mt + 4 * q4;
    #pragma unroll
    for (int nt = 0; nt < 4; ++nt) {
      const int ii = i0 + 16 * nt + cl;
      #pragma unroll
      for (int r = 0; r < 4; ++r) {
        size_t idx = ((size_t)b * CC + (c + r)) * LL + ii;
        out[idx] = gam * O[mt][nt][r] * inv_l[nt] + x[idx];
      }
    }
  }
}

extern "C" void kernel_launch(void* const* d_in, const int* in_sizes, int n_in,
                              void* d_out, int out_size, void* d_ws, size_t ws_size,
                              hipStream_t stream) {
  const float* x     = (const float*)d_in[0];
  const float* Wq    = (const float*)d_in[1];
  const float* bq    = (const float*)d_in[2];
  const float* Wk    = (const float*)d_in[3];
  const float* bk    = (const float*)d_in[4];
  const float* Wv    = (const float*)d_in[5];
  const float* bv    = (const float*)d_in[6];
  const float* gamma = (const float*)d_in[7];
  float* out = (float*)d_out;

  // workspace: qT (1MB) | kT (1MB) | v (8MB), all bf16
  unsigned short* qT = (unsigned short*)d_ws;
  unsigned short* kT = qT + (size_t)BB * LL * DD;
  unsigned short* vv = kT + (size_t)BB * LL * DD;

  qkv_kernel<<<BB * 64 * 8, 256, 0, stream>>>(x, Wq, bq, Wk, bk, Wv, bv, qT, kT, vv);
  attn_kernel<<<BB * 64, 256, 0, stream>>>(qT, kT, vv, x, gamma, out);
}

// Round 2
// 279.880 us; speedup vs baseline: 1.0799x; 1.0799x over previous
//
#include <hip/hip_runtime.h>
#include <math.h>

#define BB 4
#define CC 256
#define LL 4096
#define DD 32   // q/k channels

typedef __attribute__((ext_vector_type(8))) short short8;   // 8 bf16 (4 VGPRs)
typedef __attribute__((ext_vector_type(4))) float f32x4;
typedef __attribute__((ext_vector_type(4))) unsigned int uint4v;

__device__ inline unsigned short f2bf(float f) {
  union { float f; unsigned u; } v; v.f = f;
  unsigned r = v.u + 0x7fffu + ((v.u >> 16) & 1u);  // RNE
  return (unsigned short)(r >> 16);
}

// ---------------- kernel 0: transpose-cast x -> xT[b][l][c] bf16; W -> bf16 ----------------
// blocks 0..1023: x transpose (64c x 64l tiles). blocks 1024..1025: W conversion.
__global__ __launch_bounds__(256) void prep_kernel(
    const float* __restrict__ x,
    const float* __restrict__ Wq, const float* __restrict__ Wk, const float* __restrict__ Wv,
    unsigned short* __restrict__ xT, unsigned short* __restrict__ Wbf)
{
  const int t = threadIdx.x;
  const int blk = blockIdx.x;
  if (blk >= 1024) {
    int e = (blk - 1024) * 40960 + t;       // 320*256 = 81920 total
    for (int rr = 0; rr < 160; ++rr, e += 256) {
      float v = (e < 8192) ? Wq[e] : (e < 16384) ? Wk[e - 8192] : Wv[e - 16384];
      Wbf[e] = f2bf(v);
    }
    return;
  }
  __shared__ unsigned int T32[64][33];      // c-pairs packed; 33 stride: conflict-free
  const int b  = blk >> 8;
  const int c0 = ((blk >> 6) & 3) * 64;
  const int l0 = (blk & 63) * 64;
  const int l  = t & 63;
  const int cg = t >> 6;
  #pragma unroll
  for (int rr = 0; rr < 8; ++rr) {
    const int c2 = cg * 8 + rr;             // c pair index 0..31
    const float* p = x + ((size_t)(b * CC + c0 + 2 * c2)) * LL + l0 + l;
    unsigned lo = f2bf(p[0]);
    unsigned hi = f2bf(p[LL]);
    T32[l][c2] = lo | (hi << 16);
  }
  __syncthreads();
  const int i = t >> 2;
  const int q = t & 3;
  unsigned int r0[8];
  #pragma unroll
  for (int u = 0; u < 8; ++u) r0[u] = T32[i][q * 8 + u];
  unsigned short* dst = xT + ((size_t)b * LL + l0 + i) * CC + c0 + q * 16;
  uint4v v0 = { r0[0], r0[1], r0[2], r0[3] };
  uint4v v1 = { r0[4], r0[5], r0[6], r0[7] };
  *(uint4v*)dst = v0;
  *(uint4v*)(dst + 8) = v1;
}

// ---------------- kernel 1: QKV projection as MFMA GEMM ----------------
// out[o][i] = sum_c W[o][c] xT[i][c] + bias.  M=320 (5 tiles of 64), N=4096 (tiles of 128), K=256.
// grid = 5 * 32 * 4 blocks, 256 thr (4 waves; wave w owns i-range 32w.., all 64 o).
__global__ __launch_bounds__(256) void qkv_kernel(
    const unsigned short* __restrict__ xT, const unsigned short* __restrict__ Wbf,
    const float* __restrict__ bq, const float* __restrict__ bk, const float* __restrict__ bv,
    unsigned short* __restrict__ qT, unsigned short* __restrict__ kT,
    unsigned short* __restrict__ vv)
{
  const int t = threadIdx.x;
  const int w = t >> 6, lane = t & 63, cl = lane & 15, q4 = lane >> 4;
  int blk = blockIdx.x;
  const int Mt = blk % 5; blk /= 5;
  const int it = blk & 31;
  const int b  = blk >> 5;
  const int o0 = Mt * 64;
  const int i0 = it * 128 + w * 32;

  const f32x4 zero = {0.f, 0.f, 0.f, 0.f};
  f32x4 acc[4][2];
  #pragma unroll
  for (int mt = 0; mt < 4; ++mt)
    #pragma unroll
    for (int nt = 0; nt < 2; ++nt) acc[mt][nt] = zero;

  const unsigned short* abase = Wbf + (size_t)(o0 + cl) * CC;
  const unsigned short* bbase = xT + ((size_t)b * LL + i0 + cl) * CC;

  #pragma unroll
  for (int ks = 0; ks < 8; ++ks) {
    const int kof = ks * 32 + q4 * 8;
    short8 a[4], bfr[2];
    #pragma unroll
    for (int mt = 0; mt < 4; ++mt) a[mt] = *(const short8*)(abase + mt * 16 * CC + kof);
    #pragma unroll
    for (int nt = 0; nt < 2; ++nt) bfr[nt] = *(const short8*)(bbase + nt * 16 * CC + kof);
    #pragma unroll
    for (int mt = 0; mt < 4; ++mt)
      #pragma unroll
      for (int nt = 0; nt < 2; ++nt)
        acc[mt][nt] = __builtin_amdgcn_mfma_f32_16x16x32_bf16(a[mt], bfr[nt], acc[mt][nt], 0, 0, 0);
  }

  #pragma unroll
  for (int mt = 0; mt < 4; ++mt) {
    #pragma unroll
    for (int r = 0; r < 4; ++r) {
      const int o = o0 + 16 * mt + 4 * q4 + r;
      const float bias = (o < 32) ? bq[o] : (o < 64) ? bk[o - 32] : bv[o - 64];
      #pragma unroll
      for (int nt = 0; nt < 2; ++nt) {
        const int i = i0 + 16 * nt + cl;
        const unsigned short bfv = f2bf(acc[mt][nt][r] + bias);
        if (o < 32)       qT[((size_t)b * LL + i) * DD + o] = bfv;
        else if (o < 64)  kT[((size_t)b * LL + i) * DD + (o - 32)] = bfv;
        else {
          // key-interleaved storage permutation (must match attn's P column order)
          const int ip = (i & ~63) + 4 * (i & 15) + ((i >> 4) & 3);
          vv[((size_t)b * CC + (o - 64)) * LL + ip] = bfv;
        }
      }
    }
  }
}

// ---------------- kernel 2: flash attention (no-max softmax) + residual ----------------
// grid BB*64, 512 thr = 8 waves. wave w: g=w&3, kh=w>>2.
// S: wave computes S rows 16g..16g+15 for key sub-tiles nt=2kh,2kh+1.
// PV: wave accumulates O[ch 64g..64g+63][all 64 q] over key-half kh; merged via LDS at end.
__global__ __launch_bounds__(512) void attn_kernel(
    const unsigned short* __restrict__ qT, const unsigned short* __restrict__ kT,
    const unsigned short* __restrict__ vv, const float* __restrict__ x,
    const float* __restrict__ gamma_p, float* __restrict__ out)
{
  __shared__ __align__(16) unsigned short P_lds[64][72];  // [query][perm key col], 144B rows
  __shared__ float l_part[2][64];
  __shared__ __align__(16) float Omrg[4][16][64][4];      // 64KB merge buffer

  const int t = threadIdx.x;
  const int w = t >> 6, lane = t & 63, cl = lane & 15, q4 = lane >> 4;
  const int g  = w & 3;
  const int kh = w >> 2;
  const int it = blockIdx.x & 63, b = blockIdx.x >> 6;
  const int i0 = it * 64;

  const short8 qa = *(const short8*)(qT + ((size_t)b * LL + i0 + 16 * g + cl) * DD + q4 * 8);
  short8 ones;
  #pragma unroll
  for (int u = 0; u < 8; ++u) ones[u] = (short)0x3F80;    // bf16 1.0

  const f32x4 zero = {0.f, 0.f, 0.f, 0.f};
  f32x4 O[4][4];
  #pragma unroll
  for (int mt = 0; mt < 4; ++mt)
    #pragma unroll
    for (int nt = 0; nt < 4; ++nt) O[mt][nt] = zero;
  f32x4 lacc = zero;

  const unsigned short* kbase = kT + ((size_t)b * LL + cl) * DD + q4 * 8;          // + (j0+16nt)*DD
  const unsigned short* vbase = vv + ((size_t)b * CC + 64 * g + cl) * LL + kh * 32 + q4 * 8;

  short8 kb[2], va[4], va_n[4];
  #pragma unroll
  for (int tt = 0; tt < 2; ++tt)
    kb[tt] = *(const short8*)(kbase + (size_t)(16 * (2 * kh + tt)) * DD);
  #pragma unroll
  for (int mt = 0; mt < 4; ++mt)
    va[mt] = *(const short8*)(vbase + (size_t)mt * 16 * LL);

  for (int jt = 0; jt < 64; ++jt) {
    // S = Q K^T for this wave's two 16x16 sub-tiles
    const f32x4 s0 = __builtin_amdgcn_mfma_f32_16x16x32_bf16(qa, kb[0], zero, 0, 0, 0);
    const f32x4 s1 = __builtin_amdgcn_mfma_f32_16x16x32_bf16(qa, kb[1], zero, 0, 0, 0);

    // prefetch next tile's K fragments (kb consumed above)
    const int j0n = ((jt + 1) & 63) * 64;
    #pragma unroll
    for (int tt = 0; tt < 2; ++tt)
      kb[tt] = *(const short8*)(kbase + (size_t)(j0n + 16 * (2 * kh + tt)) * DD);

    // no-max softmax numerator: P = exp(s); pack pair -> one b32 LDS write per row
    const int row = 16 * g + 4 * q4;
    #pragma unroll
    for (int r = 0; r < 4; ++r) {
      const unsigned lo = f2bf(__expf(s0[r]));
      const unsigned hi = f2bf(__expf(s1[r]));
      *(unsigned int*)&P_lds[row + r][4 * cl + 2 * kh] = lo | (hi << 16);
    }
    __syncthreads();

    // P fragments (B-operand): contiguous 16B thanks to interleaved storage
    short8 pb[4];
    #pragma unroll
    for (int nt = 0; nt < 4; ++nt)
      pb[nt] = *(const short8*)&P_lds[16 * nt + cl][kh * 32 + q4 * 8];

    // prefetch next tile's V fragments (covered by PV MFMAs below)
    #pragma unroll
    for (int mt = 0; mt < 4; ++mt)
      va_n[mt] = *(const short8*)(vbase + (size_t)mt * 16 * LL + j0n);

    // O += V * P^T over this wave's 32-key half
    #pragma unroll
    for (int mt = 0; mt < 4; ++mt)
      #pragma unroll
      for (int nt = 0; nt < 4; ++nt)
        O[mt][nt] = __builtin_amdgcn_mfma_f32_16x16x32_bf16(va[mt], pb[nt], O[mt][nt], 0, 0, 0);
    // row-sum l via ones-A MFMA (wave covers (query group g, key half kh))
    lacc = __builtin_amdgcn_mfma_f32_16x16x32_bf16(ones, pb[g], lacc, 0, 0, 0);

    #pragma unroll
    for (int mt = 0; mt < 4; ++mt) va[mt] = va_n[mt];

    __syncthreads();  // protect P_lds before next tile's writes
  }

  // ---- epilogue: merge key-halves, normalize, residual ----
  if (lane < 16) l_part[kh][16 * g + cl] = lacc[0];
  if (kh == 1) {
    #pragma unroll
    for (int mt = 0; mt < 4; ++mt)
      #pragma unroll
      for (int nt = 0; nt < 4; ++nt)
        *(f32x4*)&Omrg[g][mt * 4 + nt][lane][0] = O[mt][nt];
  }
  __syncthreads();
  if (kh == 0) {
    const float gam = gamma_p[0];
    float inv_l[4];
    #pragma unroll
    for (int nt = 0; nt < 4; ++nt)
      inv_l[nt] = 1.0f / (l_part[0][16 * nt + cl] + l_part[1][16 * nt + cl]);
    #pragma unroll
    for (int mt = 0; mt < 4; ++mt) {
      #pragma unroll
      for (int nt = 0; nt < 4; ++nt) {
        const f32x4 om = *(const f32x4*)&Omrg[g][mt * 4 + nt][lane][0];
        #pragma unroll
        for (int r = 0; r < 4; ++r) {
          const int ch = 64 * g + 16 * mt + 4 * q4 + r;
          const int i  = i0 + 16 * nt + cl;
          const size_t idx = ((size_t)b * CC + ch) * LL + i;
          out[idx] = gam * (O[mt][nt][r] + om[r]) * inv_l[nt] + x[idx];
        }
      }
    }
  }
}

extern "C" void kernel_launch(void* const* d_in, const int* in_sizes, int n_in,
                              void* d_out, int out_size, void* d_ws, size_t ws_size,
                              hipStream_t stream) {
  const float* x     = (const float*)d_in[0];
  const float* Wq    = (const float*)d_in[1];
  const float* bq    = (const float*)d_in[2];
  const float* Wk    = (const float*)d_in[3];
  const float* bk    = (const float*)d_in[4];
  const float* Wv    = (const float*)d_in[5];
  const float* bv    = (const float*)d_in[6];
  const float* gamma = (const float*)d_in[7];
  float* out = (float*)d_out;

  // d_out doubles as scratch until attn_kernel's final full overwrite:
  //   xT (8MB bf16) | Wbf (160KB bf16)
  unsigned short* xT  = (unsigned short*)d_out;
  unsigned short* Wbf = xT + (size_t)BB * LL * CC;

  // ws: qT (1MB) | kT (1MB) | vv (8MB, key-permuted)
  unsigned short* qT = (unsigned short*)d_ws;
  unsigned short* kT = qT + (size_t)BB * LL * DD;
  unsigned short* vv = kT + (size_t)BB * LL * DD;

  prep_kernel<<<1026, 256, 0, stream>>>(x, Wq, Wk, Wv, xT, Wbf);
  qkv_kernel<<<5 * 32 * BB, 256, 0, stream>>>(xT, Wbf, bq, bk, bv, qT, kT, vv);
  attn_kernel<<<BB * 64, 512, 0, stream>>>(qT, kT, vv, x, gamma, out);
}

// Round 3
// 235.796 us; speedup vs baseline: 1.2818x; 1.1870x over previous
//
#include <hip/hip_runtime.h>
#include <math.h>

#define BB 4
#define CC 256
#define LL 4096
#define DD 32   // q/k channels
#define LOG2E 1.44269504088896f

typedef __attribute__((ext_vector_type(8))) short short8;   // 8 bf16 (4 VGPRs)
typedef __attribute__((ext_vector_type(4))) short short4v;
typedef __attribute__((ext_vector_type(4))) float f32x4;
typedef __attribute__((ext_vector_type(4))) unsigned int uint4v;

__device__ inline unsigned short f2bf(float f) {
  union { float f; unsigned u; } v; v.f = f;
  unsigned r = v.u + 0x7fffu + ((v.u >> 16) & 1u);  // RNE
  return (unsigned short)(r >> 16);
}

// position p -> kT storage row within a 32-key group, so that P's MFMA-C layout
// matches the PV B-operand layout with V stored in NATURAL key order.
__device__ __host__ inline int sigma32(int p) {
  const int q4 = (p >> 3) & 3, u = p & 7;
  return 16 * (u >> 2) + 4 * q4 + (u & 3);
}

// ---------------- kernel 0: transpose-cast x -> xT[b][l][c] bf16; W -> bf16 ----------------
__global__ __launch_bounds__(256) void prep_kernel(
    const float* __restrict__ x,
    const float* __restrict__ Wq, const float* __restrict__ Wk, const float* __restrict__ Wv,
    unsigned short* __restrict__ xT, unsigned short* __restrict__ Wbf)
{
  const int t = threadIdx.x;
  const int blk = blockIdx.x;
  if (blk >= 1024) {
    int e = (blk - 1024) * 40960 + t;       // 320*256 = 81920 total
    for (int rr = 0; rr < 160; ++rr, e += 256) {
      float v = (e < 8192) ? Wq[e] : (e < 16384) ? Wk[e - 8192] : Wv[e - 16384];
      Wbf[e] = f2bf(v);
    }
    return;
  }
  __shared__ unsigned int T32[64][33];
  const int b  = blk >> 8;
  const int c0 = ((blk >> 6) & 3) * 64;
  const int l0 = (blk & 63) * 64;
  const int l  = t & 63;
  const int cg = t >> 6;
  #pragma unroll
  for (int rr = 0; rr < 8; ++rr) {
    const int c2 = cg * 8 + rr;
    const float* p = x + ((size_t)(b * CC + c0 + 2 * c2)) * LL + l0 + l;
    unsigned lo = f2bf(p[0]);
    unsigned hi = f2bf(p[LL]);
    T32[l][c2] = lo | (hi << 16);
  }
  __syncthreads();
  const int i = t >> 2;
  const int q = t & 3;
  unsigned int r0[8];
  #pragma unroll
  for (int u = 0; u < 8; ++u) r0[u] = T32[i][q * 8 + u];
  unsigned short* dst = xT + ((size_t)b * LL + l0 + i) * CC + c0 + q * 16;
  uint4v v0 = { r0[0], r0[1], r0[2], r0[3] };
  uint4v v1 = { r0[4], r0[5], r0[6], r0[7] };
  *(uint4v*)dst = v0;
  *(uint4v*)(dst + 8) = v1;
}

// ---------------- kernel 1: QKV projection as MFMA GEMM, LDS-staged coalesced stores --------
// M=320 (5 tiles of 64 o-rows), N=4096 (tiles of 128 i), K=256.
// q rows pre-scaled by log2(e); kT rows sigma-permuted; vv natural [b][c][l].
__global__ __launch_bounds__(256) void qkv_kernel(
    const unsigned short* __restrict__ xT, const unsigned short* __restrict__ Wbf,
    const float* __restrict__ bq, const float* __restrict__ bk, const float* __restrict__ bv,
    unsigned short* __restrict__ qT, unsigned short* __restrict__ kT,
    unsigned short* __restrict__ vv)
{
  __shared__ unsigned short stage[9216];   // A: [128][72] (i-major)  B: [64][144] (o-major)
  const int t = threadIdx.x;
  const int w = t >> 6, lane = t & 63, cl = lane & 15, q4 = lane >> 4;
  int blk = blockIdx.x;
  const int Mt = blk % 5; blk /= 5;
  const int it = blk & 31;
  const int b  = blk >> 5;
  const int o0 = Mt * 64;
  const int i0 = it * 128;           // block's i-range; wave covers i0 + 32w ..

  const f32x4 zero = {0.f, 0.f, 0.f, 0.f};
  f32x4 acc[4][2];
  #pragma unroll
  for (int mt = 0; mt < 4; ++mt)
    #pragma unroll
    for (int nt = 0; nt < 2; ++nt) acc[mt][nt] = zero;

  const unsigned short* abase = Wbf + (size_t)(o0 + cl) * CC;
  const unsigned short* bbase = xT + ((size_t)b * LL + i0 + 32 * w + cl) * CC;

  #pragma unroll
  for (int ks = 0; ks < 8; ++ks) {
    const int kof = ks * 32 + q4 * 8;
    short8 a[4], bfr[2];
    #pragma unroll
    for (int mt = 0; mt < 4; ++mt) a[mt] = *(const short8*)(abase + mt * 16 * CC + kof);
    #pragma unroll
    for (int nt = 0; nt < 2; ++nt) bfr[nt] = *(const short8*)(bbase + nt * 16 * CC + kof);
    #pragma unroll
    for (int mt = 0; mt < 4; ++mt)
      #pragma unroll
      for (int nt = 0; nt < 2; ++nt)
        acc[mt][nt] = __builtin_amdgcn_mfma_f32_16x16x32_bf16(a[mt], bfr[nt], acc[mt][nt], 0, 0, 0);
  }

  if (Mt == 0) {
    // ---- q (o<32, scaled) + k (o in 32..64): stage as [i][o], stride 72 ----
    #pragma unroll
    for (int mt = 0; mt < 4; ++mt) {
      const float bias = (16 * mt < 32) ? 0.f : 0.f;  // bias applied per-o below
      #pragma unroll
      for (int nt = 0; nt < 2; ++nt) {
        const int i = 32 * w + 16 * nt + cl;
        short4v pk;
        #pragma unroll
        for (int r = 0; r < 4; ++r) {
          const int o = 16 * mt + 4 * q4 + r;
          float v = acc[mt][nt][r] + ((o < 32) ? bq[o] : bk[o - 32]);
          if (o < 32) v *= LOG2E;
          pk[r] = (short)f2bf(v);
        }
        *(short4v*)&stage[i * 72 + 16 * mt + 4 * q4] = pk;
      }
    }
    __syncthreads();
    // threads: i = t>>1 (0..127), which = t&1 (0=q row, 1=k row): 64B each
    const int i = t >> 1, which = t & 1;
    uint4v d0 = *(const uint4v*)&stage[i * 72 + which * 32];
    uint4v d1 = *(const uint4v*)&stage[i * 72 + which * 32 + 8];
    uint4v d2 = *(const uint4v*)&stage[i * 72 + which * 32 + 16];
    uint4v d3 = *(const uint4v*)&stage[i * 72 + which * 32 + 24];
    const int gi = i0 + i;
    unsigned short* dst;
    if (which == 0) {
      dst = qT + ((size_t)b * LL + gi) * DD;
    } else {
      const int row = (gi & ~31) + sigma32(gi & 31);
      dst = kT + ((size_t)b * LL + row) * DD;
    }
    *(uint4v*)dst = d0; *(uint4v*)(dst + 8) = d1;
    *(uint4v*)(dst + 16) = d2; *(uint4v*)(dst + 24) = d3;
  } else {
    // ---- v (64 rows): stage as [o][i], stride 144 ----
    #pragma unroll
    for (int mt = 0; mt < 4; ++mt)
      #pragma unroll
      for (int nt = 0; nt < 2; ++nt) {
        const int i = 32 * w + 16 * nt + cl;
        #pragma unroll
        for (int r = 0; r < 4; ++r) {
          const int o = 16 * mt + 4 * q4 + r;
          stage[o * 144 + i] = f2bf(acc[mt][nt][r] + bv[o0 - 64 + o]);
        }
      }
    __syncthreads();
    // threads: ch = t>>2 (0..63), part = t&3: 64B each
    const int ch = t >> 2, part = t & 3;
    uint4v d0 = *(const uint4v*)&stage[ch * 144 + part * 32];
    uint4v d1 = *(const uint4v*)&stage[ch * 144 + part * 32 + 8];
    uint4v d2 = *(const uint4v*)&stage[ch * 144 + part * 32 + 16];
    uint4v d3 = *(const uint4v*)&stage[ch * 144 + part * 32 + 24];
    unsigned short* dst = vv + ((size_t)b * CC + (o0 - 64) + ch) * LL + i0 + part * 32;
    *(uint4v*)dst = d0; *(uint4v*)(dst + 8) = d1;
    *(uint4v*)(dst + 16) = d2; *(uint4v*)(dst + 24) = d3;
  }
}

// ---------------- kernel 2: barrier-free flash attention + residual ----------------
// grid BB*64 blocks, 512 thr = 8 waves: m4 = w&3 (64-ch group), kh = w>>2 (2048-key half).
// Each wave: S^T = K*Q^T (8 MFMAs) -> P in-register (exp2 + v_perm pack) -> PV (16 MFMAs)
// + 1 ones-MFMA for l. NO LDS / NO barriers in the K-loop.
__global__ __launch_bounds__(512, 2) void attn_kernel(
    const unsigned short* __restrict__ qT, const unsigned short* __restrict__ kT,
    const unsigned short* __restrict__ vv, const float* __restrict__ x,
    const float* __restrict__ gamma_p, float* __restrict__ out)
{
  __shared__ __align__(16) float Omrg[4][16][64][4];   // 64KB epilogue merge
  __shared__ float l_part[2][64];

  const int t = threadIdx.x;
  const int w = t >> 6, lane = t & 63, cl = lane & 15, q4 = lane >> 4;
  const int m4 = w & 3;
  const int kh = w >> 2;
  const int it = blockIdx.x & 63, b = blockIdx.x >> 6;
  const int i0 = it * 64;

  // Q as B-operand: B[k=ch][n=query], one frag per 16-query n-tile
  short8 qa[4];
  #pragma unroll
  for (int nt = 0; nt < 4; ++nt)
    qa[nt] = *(const short8*)(qT + ((size_t)b * LL + i0 + 16 * nt + cl) * DD + q4 * 8);

  short8 ones;
  #pragma unroll
  for (int u = 0; u < 8; ++u) ones[u] = (short)0x3F80;

  const f32x4 zero = {0.f, 0.f, 0.f, 0.f};
  f32x4 O[4][4];
  #pragma unroll
  for (int mt = 0; mt < 4; ++mt)
    #pragma unroll
    for (int nt = 0; nt < 4; ++nt) O[mt][nt] = zero;
  f32x4 lacc = zero;

  const unsigned short* kbase = kT + ((size_t)b * LL + kh * 2048 + cl) * DD + q4 * 8;
  const unsigned short* vbase = vv + ((size_t)b * CC + 64 * m4 + cl) * LL + kh * 2048 + q4 * 8;

  short8 kb[2], va[4], kbn[2], van[4];
  #pragma unroll
  for (int mt = 0; mt < 2; ++mt) kb[mt] = *(const short8*)(kbase + (size_t)(16 * mt) * DD);
  #pragma unroll
  for (int mt = 0; mt < 4; ++mt) va[mt] = *(const short8*)(vbase + (size_t)mt * 16 * LL);

  for (int ks = 0; ks < 64; ++ks) {
    const int nofs = ((ks + 1) & 63) * 32;
    // prefetch next kstep (no barriers anywhere -> stays in flight freely)
    #pragma unroll
    for (int mt = 0; mt < 2; ++mt)
      kbn[mt] = *(const short8*)(kbase + (size_t)(nofs + 16 * mt) * DD);
    #pragma unroll
    for (int mt = 0; mt < 4; ++mt)
      van[mt] = *(const short8*)(vbase + (size_t)mt * 16 * LL + nofs);

    // S^T for 64 queries x 32 keys (storage order)
    f32x4 s0[4], s1[4];
    #pragma unroll
    for (int nt = 0; nt < 4; ++nt) {
      s0[nt] = __builtin_amdgcn_mfma_f32_16x16x32_bf16(kb[0], qa[nt], zero, 0, 0, 0);
      s1[nt] = __builtin_amdgcn_mfma_f32_16x16x32_bf16(kb[1], qa[nt], zero, 0, 0, 0);
    }

    // P = exp2(S^T) packed straight into PV B-frags (hi16 truncation via v_perm)
    union { short8 s; uint4v u; } pb[4];
    #pragma unroll
    for (int nt = 0; nt < 4; ++nt) {
      float e0[4], e1[4];
      #pragma unroll
      for (int r = 0; r < 4; ++r) { e0[r] = exp2f(s0[nt][r]); e1[r] = exp2f(s1[nt][r]); }
      pb[nt].u.x = __builtin_amdgcn_perm(__float_as_uint(e0[1]), __float_as_uint(e0[0]), 0x07060302);
      pb[nt].u.y = __builtin_amdgcn_perm(__float_as_uint(e0[3]), __float_as_uint(e0[2]), 0x07060302);
      pb[nt].u.z = __builtin_amdgcn_perm(__float_as_uint(e1[1]), __float_as_uint(e1[0]), 0x07060302);
      pb[nt].u.w = __builtin_amdgcn_perm(__float_as_uint(e1[3]), __float_as_uint(e1[2]), 0x07060302);
    }

    // O += V * P   (V natural order thanks to sigma-permuted kT rows)
    #pragma unroll
    for (int mt = 0; mt < 4; ++mt)
      #pragma unroll
      for (int nt = 0; nt < 4; ++nt)
        O[mt][nt] = __builtin_amdgcn_mfma_f32_16x16x32_bf16(va[mt], pb[nt].s, O[mt][nt], 0, 0, 0);
    // l partial for this wave's query quarter
    lacc = __builtin_amdgcn_mfma_f32_16x16x32_bf16(ones, pb[m4].s, lacc, 0, 0, 0);

    #pragma unroll
    for (int mt = 0; mt < 2; ++mt) kb[mt] = kbn[mt];
    #pragma unroll
    for (int mt = 0; mt < 4; ++mt) va[mt] = van[mt];
  }

  // ---- epilogue: merge key-halves, normalize, residual ----
  if (lane < 16) l_part[kh][16 * m4 + lane] = lacc[0];
  if (kh == 1) {
    #pragma unroll
    for (int mt = 0; mt < 4; ++mt)
      #pragma unroll
      for (int nt = 0; nt < 4; ++nt)
        *(f32x4*)&Omrg[m4][mt * 4 + nt][lane][0] = O[mt][nt];
  }
  __syncthreads();
  if (kh == 0) {
    const float gam = gamma_p[0];
    float inv_l[4];
    #pragma unroll
    for (int nt = 0; nt < 4; ++nt)
      inv_l[nt] = 1.0f / (l_part[0][16 * nt + cl] + l_part[1][16 * nt + cl]);
    #pragma unroll
    for (int mt = 0; mt < 4; ++mt) {
      #pragma unroll
      for (int nt = 0; nt < 4; ++nt) {
        const f32x4 om = *(const f32x4*)&Omrg[m4][mt * 4 + nt][lane][0];
        #pragma unroll
        for (int r = 0; r < 4; ++r) {
          const int ch = 64 * m4 + 16 * mt + 4 * q4 + r;
          const int i  = i0 + 16 * nt + cl;
          const size_t idx = ((size_t)b * CC + ch) * LL + i;
          out[idx] = gam * (O[mt][nt][r] + om[r]) * inv_l[nt] + x[idx];
        }
      }
    }
  }
}

extern "C" void kernel_launch(void* const* d_in, const int* in_sizes, int n_in,
                              void* d_out, int out_size, void* d_ws, size_t ws_size,
                              hipStream_t stream) {
  const float* x     = (const float*)d_in[0];
  const float* Wq    = (const float*)d_in[1];
  const float* bq    = (const float*)d_in[2];
  const float* Wk    = (const float*)d_in[3];
  const float* bk    = (const float*)d_in[4];
  const float* Wv    = (const float*)d_in[5];
  const float* bv    = (const float*)d_in[6];
  const float* gamma = (const float*)d_in[7];
  float* out = (float*)d_out;

  // d_out doubles as scratch until attn_kernel's final full overwrite:
  unsigned short* xT  = (unsigned short*)d_out;            // 8MB
  unsigned short* Wbf = xT + (size_t)BB * LL * CC;         // 160KB

  // ws: qT (1MB) | kT (1MB, sigma-permuted rows) | vv (8MB, natural)
  unsigned short* qT = (unsigned short*)d_ws;
  unsigned short* kT = qT + (size_t)BB * LL * DD;
  unsigned short* vv = kT + (size_t)BB * LL * DD;

  prep_kernel<<<1026, 256, 0, stream>>>(x, Wq, Wk, Wv, xT, Wbf);
  qkv_kernel<<<5 * 32 * BB, 256, 0, stream>>>(xT, Wbf, bq, bk, bv, qT, kT, vv);
  attn_kernel<<<BB * 64, 512, 0, stream>>>(qT, kT, vv, x, gamma, out);
}